// Round 12
// baseline (445.937 us; speedup 1.0000x reference)
//
#include <hip/hip_runtime.h>
#include <math.h>

// Problem constants (fixed by reference setup_inputs)
#define NODES 16384   // bs*N
#define CIN   256     // C (= GEMM K)
#define HD    512     // H*D (= GEMM N)
#define NPOS  4096    // N
#define NHEAD 8       // H
#define DDIM  64      // D
#define HN    (NODES * CIN)   // h elements = 4194304
#define WN    (HD * CIN)      // one W = 131072

typedef float f32x4 __attribute__((ext_vector_type(4)));
typedef unsigned int u32x4 __attribute__((ext_vector_type(4)));
typedef short s16x8 __attribute__((ext_vector_type(8)));   // 8 bf16 = 4 VGPRs

__device__ inline unsigned short f2bf(float f) {   // RNE f32 -> bf16 bits
  unsigned int u = __float_as_uint(f);
  u += 0x7fffu + ((u >> 16) & 1u);
  return (unsigned short)(u >> 16);
}

// ---------------------------------------------------------------------------
// Convert h, Wq, Wk, Wv (fp32) -> bf16 packed in ws; threads t < E also do
// the dst histogram AND record this edge's rank within its dst bucket
// (atomicAdd return value) -> placement later needs no atomics.
// ---------------------------------------------------------------------------
__global__ __launch_bounds__(256) void conv_rank_kernel(
    const float* __restrict__ h, const float* __restrict__ wq,
    const float* __restrict__ wk, const float* __restrict__ wv,
    unsigned short* __restrict__ out,
    const int* __restrict__ dst, int* __restrict__ count,
    int* __restrict__ rank, int E) {
  int t = blockIdx.x * 256 + threadIdx.x;
  if (t < E) rank[t] = atomicAdd(&count[dst[t]], 1);

  size_t e = (size_t)t * 8;
  const float* s;
  size_t off;
  if (e < HN)               { s = h;  off = e; }
  else if (e < HN + WN)     { s = wq; off = e - HN; }
  else if (e < HN + 2 * WN) { s = wk; off = e - HN - WN; }
  else                      { s = wv; off = e - HN - 2 * WN; }
  float4 f0 = *(const float4*)(s + off);
  float4 f1 = *(const float4*)(s + off + 4);
  u32x4 o;
  o[0] = f2bf(f0.x) | ((unsigned int)f2bf(f0.y) << 16);
  o[1] = f2bf(f0.z) | ((unsigned int)f2bf(f0.w) << 16);
  o[2] = f2bf(f1.x) | ((unsigned int)f2bf(f1.y) << 16);
  o[3] = f2bf(f1.z) | ((unsigned int)f2bf(f1.w) << 16);
  *(u32x4*)(out + e) = o;
}

// ---------------------------------------------------------------------------
// Prefix scan of per-dst counts (single block, 256 threads, 64 counts each).
// 256 partials scanned by wave 0 via shfl_up tree.
// ---------------------------------------------------------------------------
__global__ __launch_bounds__(256) void scan_kernel(
    const int* __restrict__ count, int* __restrict__ offset) {
  __shared__ int psum[256];
  __shared__ int pref[256];
  int t = threadIdx.x;
  int base = t * (NODES / 256);
  int s = 0;
  for (int i = 0; i < NODES / 256; ++i) s += count[base + i];
  psum[t] = s;
  __syncthreads();
  if (t < 64) {
    int a0 = psum[4 * t], a1 = psum[4 * t + 1];
    int a2 = psum[4 * t + 2], a3 = psum[4 * t + 3];
    int loc = a0 + a1 + a2 + a3;
    int sc = loc;
#pragma unroll
    for (int d = 1; d < 64; d <<= 1) {
      int v = __shfl_up(sc, d);
      if (t >= d) sc += v;
    }
    int excl = sc - loc;
    pref[4 * t]     = excl;
    pref[4 * t + 1] = excl + a0;
    pref[4 * t + 2] = excl + a0 + a1;
    pref[4 * t + 3] = excl + a0 + a1 + a2;
  }
  __syncthreads();
  int off = pref[t];
  for (int i = 0; i < NODES / 256; ++i) {
    offset[base + i] = off;
    off += count[base + i];
  }
  if (t == 255) offset[NODES] = off;
}

// ---------------------------------------------------------------------------
// Atomic-free placement: slot = offset[dst] + rank (rank from conv pass).
// ---------------------------------------------------------------------------
__global__ __launch_bounds__(256) void place_kernel(
    const int* __restrict__ src, const int* __restrict__ dst,
    const int* __restrict__ offset, const int* __restrict__ rank,
    int* __restrict__ srcs, int E) {
  int t = blockIdx.x * 256 + threadIdx.x;
  if (t < E) srcs[offset[dst[t]] + rank[t]] = src[t];
}

// ---------------------------------------------------------------------------
// MFMA GEMM with fused RoPE epilogue, HEAD-MAJOR output:
// C element (row, col) -> C[head][row][col&63] with head = col>>6, i.e.
// C + head*(NODES*64) + row*64 + dc.  (Node kernel phases gathers by head so
// each head-phase's K_h+V_h hot set is 4.2 MB ~ one XCD L2.)
// 128x128 tile, 4 waves (2x2 of 64x64), BK=32, 2-phase dbuf pipeline.
// RoPE fusion (z<2): head = bx*2+wc; ni=0/1 x-axis pair (i, i+16), ni=2/3
// y-axis; rem = (row&4095)*8+head; angle = pos[b,n,axis]*64*invf.
// ---------------------------------------------------------------------------
__global__ __launch_bounds__(256) void gemm_mfma_kernel(
    const unsigned short* __restrict__ hb,
    const unsigned short* __restrict__ wb,
    const float* __restrict__ pos,
    unsigned short* __restrict__ Qb, unsigned short* __restrict__ Kb,
    unsigned short* __restrict__ Vb) {
  const int z = blockIdx.z;
  const unsigned short* B = wb + (size_t)z * WN;
  unsigned short* C = z == 0 ? Qb : (z == 1 ? Kb : Vb);

  __shared__ __align__(16) unsigned short As[2][128 * 32];
  __shared__ __align__(16) unsigned short Bs[2][128 * 32];

  const int tid = threadIdx.x;
  const int lane = tid & 63, w = tid >> 6;
  const int row0 = blockIdx.y * 128, col0 = blockIdx.x * 128;
  const int wr = w >> 1, wc = w & 1;

  const int r_l = lane >> 2;
  const int kc = (lane & 3) * 8;

  f32x4 acc[4][4] = {};

#define STAGE(bufi, kt)                                                        \
  {                                                                            \
    _Pragma("unroll") for (int u = 0; u < 2; ++u) {                            \
      int blk = u * 4 + w;                                                     \
      int r = blk * 16 + r_l;                                                  \
      __builtin_amdgcn_global_load_lds(                                        \
          (const __attribute__((address_space(1))) void*)(hb +                 \
              (size_t)(row0 + r) * CIN + (kt) + kc),                           \
          (__attribute__((address_space(3))) void*)(&As[bufi][blk * 512]),     \
          16, 0, 0);                                                           \
      __builtin_amdgcn_global_load_lds(                                        \
          (const __attribute__((address_space(1))) void*)(B +                  \
              (size_t)(col0 + r) * CIN + (kt) + kc),                           \
          (__attribute__((address_space(3))) void*)(&Bs[bufi][blk * 512]),     \
          16, 0, 0);                                                           \
    }                                                                          \
  }

  STAGE(0, 0);
  __syncthreads();

  int cur = 0;
  for (int t = 0; t < 8; ++t) {
    if (t < 7) STAGE(cur ^ 1, (t + 1) * 32);   // prefetch overlaps compute

    s16x8 af[4], bfr[4];
#pragma unroll
    for (int mi = 0; mi < 4; ++mi)
      af[mi] = *(const s16x8*)(&As[cur][(wr * 64 + mi * 16 + (lane & 15)) * 32 + (lane >> 4) * 8]);
#pragma unroll
    for (int ni = 0; ni < 4; ++ni)
      bfr[ni] = *(const s16x8*)(&Bs[cur][(wc * 64 + ni * 16 + (lane & 15)) * 32 + (lane >> 4) * 8]);
#pragma unroll
    for (int mi = 0; mi < 4; ++mi)
#pragma unroll
      for (int ni = 0; ni < 4; ++ni)
        acc[mi][ni] = __builtin_amdgcn_mfma_f32_16x16x32_bf16(
            af[mi], bfr[ni], acc[mi][ni], 0, 0, 0);

    __syncthreads();
    cur ^= 1;
  }
#undef STAGE

  // Epilogue. C/D layout: col = lane&15, row = (lane>>4)*4 + reg  [m89/m91]
  const int head = blockIdx.x * 2 + wc;
  // invf = 10000^(-(lane&15)/16) = exp2(-(lane&15) * log2(10000)/16)
  const float invf = exp2f(-(float)(lane & 15) * 0.83048202372184f);
  unsigned short* Ch = C + (size_t)head * (NODES * DDIM) + (lane & 15);

#pragma unroll
  for (int mi = 0; mi < 4; ++mi) {
#pragma unroll
    for (int r = 0; r < 4; ++r) {
      int row = row0 + wr * 64 + mi * 16 + (lane >> 4) * 4 + r;
      float v0 = acc[mi][0][r], v1 = acc[mi][1][r];
      float v2 = acc[mi][2][r], v3 = acc[mi][3][r];
      if (z < 2) {   // wave-uniform branch: RoPE for Q and K
        int b = row >> 12;
        int rem = ((row & 4095) << 3) + head;      // per-batch 64-chunk index
        int n = rem & (NPOS - 1);
        const float* pp = pos + ((size_t)((b << 12) + n)) * 2;
        float a0 = pp[0] * 64.0f * invf;
        float a1 = pp[1] * 64.0f * invf;
        float s0, c0, s1, c1;
        sincosf(a0, &s0, &c0);
        sincosf(a1, &s1, &c1);
        float nx0 = v0 * c0 - v1 * s0;
        float nx1 = v1 * c0 + v0 * s0;
        float ny0 = v2 * c1 - v3 * s1;
        float ny1 = v3 * c1 + v2 * s1;
        v0 = nx0; v1 = nx1; v2 = ny0; v3 = ny1;
      }
      unsigned short* cp = Ch + (size_t)row * DDIM;   // head-major row slice
      cp[0]  = f2bf(v0);
      cp[16] = f2bf(v1);
      cp[32] = f2bf(v2);
      cp[48] = f2bf(v3);
    }
  }
}

// ---------------------------------------------------------------------------
// Node-centric attention, head-phased. Grid (NODES/4, NHEAD); dispatch is
// x-major so all blocks of head 0 run before head 1 etc: hot set per phase =
// K_h+V_h = 4.2 MB ~ one XCD L2 (vs 33.6 MB before). Each wave owns one
// (dst, head): lanes 0-31 edge-slot 0, 32-63 edge-slot 1; dl = lane&31 is
// the dim-pair (2 dims). No barriers, no LDS, VGPR-light (32 waves/CU).
// Q/srcs loads are non-temporal (read-once streams, keep L2 for K/V).
// ---------------------------------------------------------------------------
__global__ __launch_bounds__(256) void node_kernel(
    const unsigned short* __restrict__ Qb, const unsigned short* __restrict__ Kb,
    const unsigned short* __restrict__ Vb,
    const int* __restrict__ srcs, const int* __restrict__ offset,
    float* __restrict__ out) {
  const int w = threadIdx.x >> 6, lane = threadIdx.x & 63;
  const int n = blockIdx.x * 4 + w;
  const int hh = blockIdx.y;
  const int el = lane >> 5, dl = lane & 31;

  const unsigned short* Qh = Qb + (size_t)hh * (NODES * DDIM);
  const unsigned short* Kh = Kb + (size_t)hh * (NODES * DDIM);
  const unsigned short* Vh = Vb + (size_t)hh * (NODES * DDIM);

  const int beg = offset[n], end = offset[n + 1];

  unsigned int qu = __builtin_nontemporal_load(
      (const unsigned int*)(Qh + (size_t)n * DDIM + dl * 2));
  float q0 = __uint_as_float(qu << 16);
  float q1 = __uint_as_float(qu & 0xffff0000u);

  float a0 = 0.f, a1 = 0.f, zacc = 0.f;

  for (int i = beg; i + el < end; i += 2) {
    int s = __builtin_nontemporal_load(&srcs[i + el]);
    unsigned int ku = *(const unsigned int*)(Kh + (size_t)s * DDIM + dl * 2);
    float dot = __uint_as_float(ku << 16) * q0 +
                __uint_as_float(ku & 0xffff0000u) * q1;
    dot += __shfl_xor(dot, 1);
    dot += __shfl_xor(dot, 2);
    dot += __shfl_xor(dot, 4);
    dot += __shfl_xor(dot, 8);
    dot += __shfl_xor(dot, 16);
    float sc = __expf(fminf(fmaxf(dot * 0.125f, -5.0f), 5.0f));
    unsigned int vu = *(const unsigned int*)(Vh + (size_t)s * DDIM + dl * 2);
    a0 += __uint_as_float(vu << 16) * sc;
    a1 += __uint_as_float(vu & 0xffff0000u) * sc;
    zacc += sc;
  }

  // combine the two edge-slot halves (lane ^ 32)
  a0 += __shfl_xor(a0, 32);
  a1 += __shfl_xor(a1, 32);
  zacc += __shfl_xor(zacc, 32);

  if (lane < 32) {
    float inv = 1.0f / zacc;
    *(float2*)(out + (size_t)n * HD + hh * DDIM + dl * 2) =
        make_float2(a0 * inv, a1 * inv);
  }
}

extern "C" void kernel_launch(void* const* d_in, const int* in_sizes, int n_in,
                              void* d_out, int out_size, void* d_ws,
                              size_t ws_size, hipStream_t stream) {
  const float* h   = (const float*)d_in[0];
  const float* pos = (const float*)d_in[1];
  const float* Wq  = (const float*)d_in[2];
  const float* Wk  = (const float*)d_in[3];
  const float* Wv  = (const float*)d_in[4];
  const int* src   = (const int*)d_in[5];
  const int* dst   = (const int*)d_in[6];
  const int E = in_sizes[5];

  // ws layout (ushorts first, then ints)
  unsigned short* hb  = (unsigned short*)d_ws;          // HN
  unsigned short* wb  = hb + HN;                        // 3*WN
  unsigned short* Qb  = wb + 3 * WN;                    // NODES*HD (head-major)
  unsigned short* Kb  = Qb + (size_t)NODES * HD;
  unsigned short* Vb  = Kb + (size_t)NODES * HD;
  int* count  = (int*)(Vb + (size_t)NODES * HD);        // NODES
  int* offset = count + NODES;                          // NODES+1
  int* rank   = offset + NODES + 1;                     // E
  int* srcs   = rank + E;                               // E
  float* out = (float*)d_out;

  hipMemsetAsync(count, 0, NODES * sizeof(int), stream);

  conv_rank_kernel<<<(HN + 3 * WN) / 8 / 256, 256, 0, stream>>>(
      h, Wq, Wk, Wv, hb, dst, count, rank, E);

  scan_kernel<<<1, 256, 0, stream>>>(count, offset);
  place_kernel<<<(E + 255) / 256, 256, 0, stream>>>(
      src, dst, offset, rank, srcs, E);

  gemm_mfma_kernel<<<dim3(HD / 128, NODES / 128, 3), 256, 0, stream>>>(
      hb, wb, pos, Qb, Kb, Vb);

  node_kernel<<<dim3(NODES / 4, NHEAD), 256, 0, stream>>>(
      Qb, Kb, Vb, srcs, offset, out);
}

// Round 14
// 272.003 us; speedup vs baseline: 1.6395x; 1.6395x over previous
//
#include <hip/hip_runtime.h>
#include <math.h>

// Problem constants (fixed by reference setup_inputs)
#define NODES 16384   // bs*N
#define CIN   256     // C (= GEMM K)
#define HD    512     // H*D (= GEMM N)
#define NPOS  4096    // N
#define NHEAD 8       // H
#define DDIM  64      // D
#define HN    (NODES * CIN)   // h elements = 4194304
#define WN    (HD * CIN)      // one W = 131072

typedef float f32x4 __attribute__((ext_vector_type(4)));
typedef unsigned int u32x4 __attribute__((ext_vector_type(4)));
typedef short s16x8 __attribute__((ext_vector_type(8)));   // 8 bf16 = 4 VGPRs

__device__ inline unsigned short f2bf(float f) {   // RNE f32 -> bf16 bits
  unsigned int u = __float_as_uint(f);
  u += 0x7fffu + ((u >> 16) & 1u);
  return (unsigned short)(u >> 16);
}

// ---------------------------------------------------------------------------
// Convert h, Wq, Wk, Wv (fp32) -> bf16 packed in ws; threads t < E also do
// the dst histogram AND record this edge's rank within its dst bucket
// (atomicAdd return value) -> placement later needs no atomics.
// ---------------------------------------------------------------------------
__global__ __launch_bounds__(256) void conv_rank_kernel(
    const float* __restrict__ h, const float* __restrict__ wq,
    const float* __restrict__ wk, const float* __restrict__ wv,
    unsigned short* __restrict__ out,
    const int* __restrict__ dst, int* __restrict__ count,
    int* __restrict__ rank, int E) {
  int t = blockIdx.x * 256 + threadIdx.x;
  if (t < E) rank[t] = atomicAdd(&count[dst[t]], 1);

  size_t e = (size_t)t * 8;
  const float* s;
  size_t off;
  if (e < HN)               { s = h;  off = e; }
  else if (e < HN + WN)     { s = wq; off = e - HN; }
  else if (e < HN + 2 * WN) { s = wk; off = e - HN - WN; }
  else                      { s = wv; off = e - HN - 2 * WN; }
  float4 f0 = *(const float4*)(s + off);
  float4 f1 = *(const float4*)(s + off + 4);
  u32x4 o;
  o[0] = f2bf(f0.x) | ((unsigned int)f2bf(f0.y) << 16);
  o[1] = f2bf(f0.z) | ((unsigned int)f2bf(f0.w) << 16);
  o[2] = f2bf(f1.x) | ((unsigned int)f2bf(f1.y) << 16);
  o[3] = f2bf(f1.z) | ((unsigned int)f2bf(f1.w) << 16);
  *(u32x4*)(out + e) = o;
}

// ---------------------------------------------------------------------------
// Prefix scan of per-dst counts (single block, 256 threads, 64 counts each).
// ---------------------------------------------------------------------------
__global__ __launch_bounds__(256) void scan_kernel(
    const int* __restrict__ count, int* __restrict__ offset) {
  __shared__ int psum[256];
  __shared__ int pref[256];
  int t = threadIdx.x;
  int base = t * (NODES / 256);
  int s = 0;
  for (int i = 0; i < NODES / 256; ++i) s += count[base + i];
  psum[t] = s;
  __syncthreads();
  if (t < 64) {
    int a0 = psum[4 * t], a1 = psum[4 * t + 1];
    int a2 = psum[4 * t + 2], a3 = psum[4 * t + 3];
    int loc = a0 + a1 + a2 + a3;
    int sc = loc;
#pragma unroll
    for (int d = 1; d < 64; d <<= 1) {
      int v = __shfl_up(sc, d);
      if (t >= d) sc += v;
    }
    int excl = sc - loc;
    pref[4 * t]     = excl;
    pref[4 * t + 1] = excl + a0;
    pref[4 * t + 2] = excl + a0 + a1;
    pref[4 * t + 3] = excl + a0 + a1 + a2;
  }
  __syncthreads();
  int off = pref[t];
  for (int i = 0; i < NODES / 256; ++i) {
    offset[base + i] = off;
    off += count[base + i];
  }
  if (t == 255) offset[NODES] = off;
}

// ---------------------------------------------------------------------------
// Atomic-free placement: slot = offset[dst] + rank (rank from conv pass).
// ---------------------------------------------------------------------------
__global__ __launch_bounds__(256) void place_kernel(
    const int* __restrict__ src, const int* __restrict__ dst,
    const int* __restrict__ offset, const int* __restrict__ rank,
    int* __restrict__ srcs, int E) {
  int t = blockIdx.x * 256 + threadIdx.x;
  if (t < E) srcs[offset[dst[t]] + rank[t]] = src[t];
}

// ---------------------------------------------------------------------------
// MFMA GEMM with fused RoPE epilogue, HEAD-MAJOR output:
// C element (row, col) -> C[head][row][col&63], head = col>>6.
// 128x128 tile, 4 waves (2x2 of 64x64), BK=32, 2-phase dbuf pipeline.
// RoPE fusion (z<2): head = bx*2+wc; ni=0/1 x-axis pair (i, i+16), ni=2/3
// y-axis; rem = (row&4095)*8+head; angle = pos[b,n,axis]*64*invf.
// ---------------------------------------------------------------------------
__global__ __launch_bounds__(256) void gemm_mfma_kernel(
    const unsigned short* __restrict__ hb,
    const unsigned short* __restrict__ wb,
    const float* __restrict__ pos,
    unsigned short* __restrict__ Qb, unsigned short* __restrict__ Kb,
    unsigned short* __restrict__ Vb) {
  const int z = blockIdx.z;
  const unsigned short* B = wb + (size_t)z * WN;
  unsigned short* C = z == 0 ? Qb : (z == 1 ? Kb : Vb);

  __shared__ __align__(16) unsigned short As[2][128 * 32];
  __shared__ __align__(16) unsigned short Bs[2][128 * 32];

  const int tid = threadIdx.x;
  const int lane = tid & 63, w = tid >> 6;
  const int row0 = blockIdx.y * 128, col0 = blockIdx.x * 128;
  const int wr = w >> 1, wc = w & 1;

  const int r_l = lane >> 2;
  const int kc = (lane & 3) * 8;

  f32x4 acc[4][4] = {};

#define STAGE(bufi, kt)                                                        \
  {                                                                            \
    _Pragma("unroll") for (int u = 0; u < 2; ++u) {                            \
      int blk = u * 4 + w;                                                     \
      int r = blk * 16 + r_l;                                                  \
      __builtin_amdgcn_global_load_lds(                                        \
          (const __attribute__((address_space(1))) void*)(hb +                 \
              (size_t)(row0 + r) * CIN + (kt) + kc),                           \
          (__attribute__((address_space(3))) void*)(&As[bufi][blk * 512]),     \
          16, 0, 0);                                                           \
      __builtin_amdgcn_global_load_lds(                                        \
          (const __attribute__((address_space(1))) void*)(B +                  \
              (size_t)(col0 + r) * CIN + (kt) + kc),                           \
          (__attribute__((address_space(3))) void*)(&Bs[bufi][blk * 512]),     \
          16, 0, 0);                                                           \
    }                                                                          \
  }

  STAGE(0, 0);
  __syncthreads();

  int cur = 0;
  for (int t = 0; t < 8; ++t) {
    if (t < 7) STAGE(cur ^ 1, (t + 1) * 32);   // prefetch overlaps compute

    s16x8 af[4], bfr[4];
#pragma unroll
    for (int mi = 0; mi < 4; ++mi)
      af[mi] = *(const s16x8*)(&As[cur][(wr * 64 + mi * 16 + (lane & 15)) * 32 + (lane >> 4) * 8]);
#pragma unroll
    for (int ni = 0; ni < 4; ++ni)
      bfr[ni] = *(const s16x8*)(&Bs[cur][(wc * 64 + ni * 16 + (lane & 15)) * 32 + (lane >> 4) * 8]);
#pragma unroll
    for (int mi = 0; mi < 4; ++mi)
#pragma unroll
      for (int ni = 0; ni < 4; ++ni)
        acc[mi][ni] = __builtin_amdgcn_mfma_f32_16x16x32_bf16(
            af[mi], bfr[ni], acc[mi][ni], 0, 0, 0);

    __syncthreads();
    cur ^= 1;
  }
#undef STAGE

  // Epilogue. C/D layout: col = lane&15, row = (lane>>4)*4 + reg  [m89/m91]
  const int head = blockIdx.x * 2 + wc;
  const float invf = exp2f(-(float)(lane & 15) * 0.83048202372184f);
  unsigned short* Ch = C + (size_t)head * (NODES * DDIM) + (lane & 15);

#pragma unroll
  for (int mi = 0; mi < 4; ++mi) {
#pragma unroll
    for (int r = 0; r < 4; ++r) {
      int row = row0 + wr * 64 + mi * 16 + (lane >> 4) * 4 + r;
      float v0 = acc[mi][0][r], v1 = acc[mi][1][r];
      float v2 = acc[mi][2][r], v3 = acc[mi][3][r];
      if (z < 2) {   // wave-uniform branch: RoPE for Q and K
        int b = row >> 12;
        int rem = ((row & 4095) << 3) + head;      // per-batch 64-chunk index
        int n = rem & (NPOS - 1);
        const float* pp = pos + ((size_t)((b << 12) + n)) * 2;
        float a0 = pp[0] * 64.0f * invf;
        float a1 = pp[1] * 64.0f * invf;
        float s0, c0, s1, c1;
        sincosf(a0, &s0, &c0);
        sincosf(a1, &s1, &c1);
        float nx0 = v0 * c0 - v1 * s0;
        float nx1 = v1 * c0 + v0 * s0;
        float ny0 = v2 * c1 - v3 * s1;
        float ny1 = v3 * c1 + v2 * s1;
        v0 = nx0; v1 = nx1; v2 = ny0; v3 = ny1;
      }
      unsigned short* cp = Ch + (size_t)row * DDIM;   // head-major row slice
      cp[0]  = f2bf(v0);
      cp[16] = f2bf(v1);
      cp[32] = f2bf(v2);
      cp[48] = f2bf(v3);
    }
  }
}

// ---------------------------------------------------------------------------
// Node-centric attention: head-phased (r12's locality win: per-phase hot set
// K_h+V_h = 4.2 MB ~ one XCD L2) with r6's wide-load wave shape (the r12
// regression was dword loads + per-head shfls). One wave per (dst, head);
// lane = (e8, d8): 8 edges x 8-dim slices. Per iteration each lane loads
// dwordx4 K + dwordx4 V (16 B) -> wave moves 2 KB / 8 edges, same
// bytes-per-instruction as r6. Dot reduce = 3 shfls within the 8-lane dim
// group; cross-edge-group reduce done ONCE at the end (27 shfls).
// No LDS, no barriers. Q/srcs streams are non-temporal.
// ---------------------------------------------------------------------------
__global__ __launch_bounds__(256) void node_kernel(
    const unsigned short* __restrict__ Qb, const unsigned short* __restrict__ Kb,
    const unsigned short* __restrict__ Vb,
    const int* __restrict__ srcs, const int* __restrict__ offset,
    float* __restrict__ out) {
  const int w = threadIdx.x >> 6, lane = threadIdx.x & 63;
  const int n = blockIdx.x * 4 + w;
  const int hh = blockIdx.y;
  const int e8 = lane >> 3, d8 = lane & 7;

  const unsigned short* Qh = Qb + (size_t)hh * (NODES * DDIM);
  const unsigned short* Kh = Kb + (size_t)hh * (NODES * DDIM);
  const unsigned short* Vh = Vb + (size_t)hh * (NODES * DDIM);

  const int beg = offset[n], end = offset[n + 1];

  u32x4 qu = *(const u32x4*)(Qh + (size_t)n * DDIM + d8 * 8);
  float qf[8];
#pragma unroll
  for (int j = 0; j < 4; ++j) {
    qf[2 * j]     = __uint_as_float(qu[j] << 16);
    qf[2 * j + 1] = __uint_as_float(qu[j] & 0xffff0000u);
  }

  float a[8] = {0, 0, 0, 0, 0, 0, 0, 0};
  float zacc = 0.f;

  for (int it = beg; it < end; it += 8) {
    int e = it + e8;
    bool ok = e < end;
    int s = __builtin_nontemporal_load(&srcs[ok ? e : beg]);
    u32x4 ku = *(const u32x4*)(Kh + (size_t)s * DDIM + d8 * 8);
    u32x4 vu = *(const u32x4*)(Vh + (size_t)s * DDIM + d8 * 8);
    float dot = 0.f;
#pragma unroll
    for (int j = 0; j < 4; ++j) {
      dot += __uint_as_float(ku[j] << 16) * qf[2 * j];
      dot += __uint_as_float(ku[j] & 0xffff0000u) * qf[2 * j + 1];
    }
    dot += __shfl_xor(dot, 1);   // reduce over the 8 dim-lanes of this edge
    dot += __shfl_xor(dot, 2);
    dot += __shfl_xor(dot, 4);
    float sc = ok ? __expf(fminf(fmaxf(dot * 0.125f, -5.0f), 5.0f)) : 0.f;
#pragma unroll
    for (int j = 0; j < 4; ++j) {
      a[2 * j]     += __uint_as_float(vu[j] << 16) * sc;
      a[2 * j + 1] += __uint_as_float(vu[j] & 0xffff0000u) * sc;
    }
    zacc += sc;
  }

  // combine the 8 edge groups (once): lanes differing in e8 hold partials
  // of the same output dims d8*8..d8*8+7.
#pragma unroll
  for (int d = 8; d < 64; d <<= 1) {
#pragma unroll
    for (int j = 0; j < 8; ++j) a[j] += __shfl_xor(a[j], d);
    zacc += __shfl_xor(zacc, d);
  }

  if (e8 == 0) {
    float inv = 1.0f / zacc;
    float4 o0 = make_float4(a[0] * inv, a[1] * inv, a[2] * inv, a[3] * inv);
    float4 o1 = make_float4(a[4] * inv, a[5] * inv, a[6] * inv, a[7] * inv);
    float* op = out + (size_t)n * HD + hh * DDIM + d8 * 8;
    *(float4*)op = o0;
    *(float4*)(op + 4) = o1;
  }
}

extern "C" void kernel_launch(void* const* d_in, const int* in_sizes, int n_in,
                              void* d_out, int out_size, void* d_ws,
                              size_t ws_size, hipStream_t stream) {
  const float* h   = (const float*)d_in[0];
  const float* pos = (const float*)d_in[1];
  const float* Wq  = (const float*)d_in[2];
  const float* Wk  = (const float*)d_in[3];
  const float* Wv  = (const float*)d_in[4];
  const int* src   = (const int*)d_in[5];
  const int* dst   = (const int*)d_in[6];
  const int E = in_sizes[5];

  // ws layout (ushorts first, then ints)
  unsigned short* hb  = (unsigned short*)d_ws;          // HN
  unsigned short* wb  = hb + HN;                        // 3*WN
  unsigned short* Qb  = wb + 3 * WN;                    // NODES*HD (head-major)
  unsigned short* Kb  = Qb + (size_t)NODES * HD;
  unsigned short* Vb  = Kb + (size_t)NODES * HD;
  int* count  = (int*)(Vb + (size_t)NODES * HD);        // NODES
  int* offset = count + NODES;                          // NODES+1
  int* rank   = offset + NODES + 1;                     // E
  int* srcs   = rank + E;                               // E
  float* out = (float*)d_out;

  hipMemsetAsync(count, 0, NODES * sizeof(int), stream);

  conv_rank_kernel<<<(HN + 3 * WN) / 8 / 256, 256, 0, stream>>>(
      h, Wq, Wk, Wv, hb, dst, count, rank, E);

  scan_kernel<<<1, 256, 0, stream>>>(count, offset);
  place_kernel<<<(E + 255) / 256, 256, 0, stream>>>(
      src, dst, offset, rank, srcs, E);

  gemm_mfma_kernel<<<dim3(HD / 128, NODES / 128, 3), 256, 0, stream>>>(
      hb, wb, pos, Qb, Kb, Vb);

  node_kernel<<<dim3(NODES / 4, NHEAD), 256, 0, stream>>>(
      Qb, Kb, Vb, srcs, offset, out);
}